// Round 3
// baseline (469.432 us; speedup 1.0000x reference)
//
#include <hip/hip_runtime.h>

#define NB 32
#define HH 768
#define WW 768
#define PLANE (HH * WW)
#define BAND 16
#define NBANDS (HH / BAND)   // 48
#define NSTRIP (WW / 4)      // 192 threads per block (3 waves)
#define NWG (NB * NBANDS)    // 1536 blocks

// Complete output row held in rolling slot SLOT (compile-time), absolute k = KK.
#define COMPLETE_ROW(SLOT, KK)                                                        \
  {                                                                                   \
    const int orow_ = band * BAND + (KK) - 4;                                         \
    const size_t obase_ = (size_t)orow_ * WW + w0;                                    \
    _Pragma("unroll")                                                                 \
    for (int c_ = 0; c_ < 3; ++c_) {                                                  \
      float4 v_;                                                                      \
      v_.x = acc[(SLOT)][0][0]*Wm[0][c_] + acc[(SLOT)][1][0]*Wm[1][c_] + acc[(SLOT)][2][0]*Wm[2][c_]; \
      v_.y = acc[(SLOT)][0][1]*Wm[0][c_] + acc[(SLOT)][1][1]*Wm[1][c_] + acc[(SLOT)][2][1]*Wm[2][c_]; \
      v_.z = acc[(SLOT)][0][2]*Wm[0][c_] + acc[(SLOT)][1][2]*Wm[1][c_] + acc[(SLOT)][2][2]*Wm[2][c_]; \
      v_.w = acc[(SLOT)][0][3]*Wm[0][c_] + acc[(SLOT)][1][3]*Wm[1][c_] + acc[(SLOT)][2][3]*Wm[2][c_]; \
      *(float4*)(ob[c_] + obase_) = v_;                                               \
    }                                                                                 \
    _Pragma("unroll")                                                                 \
    for (int cz_ = 0; cz_ < 3; ++cz_) {                                               \
      _Pragma("unroll")                                                               \
      for (int oz_ = 0; oz_ < 4; ++oz_) acc[(SLOT)][cz_][oz_] = 0.f;                  \
    }                                                                                 \
  }

// Process one input row. JC (0..4) static phase within 5-group; IMIN/IMAX static
// kernel-row guards for band head/tail phantoms; DOCOMP literal bool.
#define DO_ROW(JC, IMIN, IMAX, DOCOMP)                                                \
  {                                                                                   \
    const int k_ = kbase + (JC);                                                      \
    const int g_ = gtop + k_;                                                         \
    const bool rowok_ = ((unsigned)g_ < (unsigned)HH);                                \
    float wv[3][8];                                                                   \
    _Pragma("unroll")                                                                 \
    for (int ch_ = 0; ch_ < 3; ++ch_) {                                               \
      float4 L_;  L_.x = 0.f;  L_.y = 0.f;  L_.z = 0.f;  L_.w = 0.f;                  \
      float4 Mv_; Mv_.x = 0.f; Mv_.y = 0.f; Mv_.z = 0.f; Mv_.w = 0.f;                 \
      float4 R_;  R_.x = 0.f;  R_.y = 0.f;  R_.z = 0.f;  R_.w = 0.f;                  \
      if (rowok_) {                                                                   \
        const float* rp_ = cb[ch_] + (g_ * WW + w0 - 4);                              \
        const float s_ = shv[ch_];                                                    \
        if (okL) { L_ = *(const float4*)rp_; L_.z += s_; L_.w += s_; }                \
        Mv_ = *(const float4*)(rp_ + 4);                                              \
        Mv_.x += s_; Mv_.y += s_; Mv_.z += s_; Mv_.w += s_;                           \
        if (okR) { R_ = *(const float4*)(rp_ + 8); R_.x += s_; R_.y += s_; }          \
      }                                                                               \
      wv[ch_][0] = L_.z;  wv[ch_][1] = L_.w;                                          \
      wv[ch_][2] = Mv_.x; wv[ch_][3] = Mv_.y; wv[ch_][4] = Mv_.z; wv[ch_][5] = Mv_.w; \
      wv[ch_][6] = R_.x;  wv[ch_][7] = R_.y;                                          \
    }                                                                                 \
    _Pragma("unroll")                                                                 \
    for (int i_ = (IMIN); i_ <= (IMAX); ++i_) {                                       \
      _Pragma("unroll")                                                               \
      for (int ch_ = 0; ch_ < 3; ++ch_) {                                             \
        _Pragma("unroll")                                                             \
        for (int tt_ = 0; tt_ < 5; ++tt_) {                                           \
          _Pragma("unroll")                                                           \
          for (int o_ = 0; o_ < 4; ++o_)                                              \
            acc[((JC) - i_ + 5) % 5][ch_][o_] += wv[ch_][o_ + tt_] * K[i_][tt_];      \
        }                                                                             \
      }                                                                               \
    }                                                                                 \
    if (DOCOMP) COMPLETE_ROW(((JC) + 1) % 5, k_);                                     \
  }

__global__ __launch_bounds__(NSTRIP, 4) void colwarp_conv_kernel(
    const float* __restrict__ im,
    const float* __restrict__ flat,
    float* __restrict__ out)
{
  // Bijective XCD swizzle (NWG % 8 == 0): consecutive work-units (adjacent
  // bands of the same image, which share 4 halo rows) land on the same XCD L2.
  const int d   = blockIdx.x;
  const int wid = (d & 7) * (NWG / 8) + (d >> 3);
  const int b    = wid / NBANDS;
  const int band = wid - b * NBANDS;

  const int t  = threadIdx.x;      // 0..191: 4-wide output strip
  const int w0 = t * 4;
  const bool okL = (w0 > 0);
  const bool okR = (w0 < WW - 4);

  // per-sample params (b block-uniform -> scalar loads / SGPRs)
  const float* f = flat + b * 37;
  float Wm[3][3], shv[3], K[5][5];
#pragma unroll
  for (int i = 0; i < 3; ++i)
#pragma unroll
    for (int j = 0; j < 3; ++j) Wm[i][j] = f[i * 3 + j];
#pragma unroll
  for (int i = 0; i < 3; ++i) shv[i] = f[9 + i];
#pragma unroll
  for (int i = 0; i < 5; ++i)
#pragma unroll
    for (int j = 0; j < 5; ++j) K[i][j] = f[12 + i * 5 + j];

  const float* cb[3] = { im  + (size_t)(b * 3 + 0) * PLANE,
                         im  + (size_t)(b * 3 + 1) * PLANE,
                         im  + (size_t)(b * 3 + 2) * PLANE };
  float* ob[3]       = { out + (size_t)(b * 3 + 0) * PLANE,
                         out + (size_t)(b * 3 + 1) * PLANE,
                         out + (size_t)(b * 3 + 2) * PLANE };

  // rolling accumulators: 5 in-flight output rows x 3 raw channels x 4 px
  float acc[5][3][4];
#pragma unroll
  for (int s = 0; s < 5; ++s)
#pragma unroll
    for (int c = 0; c < 3; ++c)
#pragma unroll
      for (int o = 0; o < 4; ++o) acc[s][c][o] = 0.f;

  const int gtop = band * BAND - 2;

  // ---- head group: k = 0..4, skip phantom output rows r < 0 (i <= j) ----
  int kbase = 0;
  DO_ROW(0, 0, 0, false);
  DO_ROW(1, 0, 1, false);
  DO_ROW(2, 0, 2, false);
  DO_ROW(3, 0, 3, false);
  DO_ROW(4, 0, 4, true);   // completes r=0

  // ---- mid groups: k = 5..14, full taps, complete every row ----
#pragma unroll 1
  for (int blk = 1; blk <= 2; ++blk) {
    kbase = blk * 5;
    DO_ROW(0, 0, 4, true);
    DO_ROW(1, 0, 4, true);
    DO_ROW(2, 0, 4, true);
    DO_ROW(3, 0, 4, true);
    DO_ROW(4, 0, 4, true);
  }

  // ---- tail group: k = 15..19, skip phantom output rows r > 15 (i >= j) ----
  kbase = 15;
  DO_ROW(0, 0, 4, true);
  DO_ROW(1, 1, 4, true);
  DO_ROW(2, 2, 4, true);
  DO_ROW(3, 3, 4, true);
  DO_ROW(4, 4, 4, true);   // completes r=15
}

extern "C" void kernel_launch(void* const* d_in, const int* in_sizes, int n_in,
                              void* d_out, int out_size, void* d_ws, size_t ws_size,
                              hipStream_t stream) {
  const float* im   = (const float*)d_in[0];
  const float* flat = (const float*)d_in[1];
  float* out        = (float*)d_out;

  colwarp_conv_kernel<<<dim3(NWG), dim3(NSTRIP), 0, stream>>>(im, flat, out);
}

// Round 4
// 113.274 us; speedup vs baseline: 4.1442x; 4.1442x over previous
//
#include <hip/hip_runtime.h>

// Problem constants (match reference)
#define NB 32
#define CH 3
#define HH 768
#define WW 768

// Tiling
#define TW 64            // output tile width
#define TH 32            // output tile height
#define SW 72            // staged width: [tw0-4, tw0+68), 16B aligned in global AND LDS
#define SH (TH + 4)      // 36 staged rows: [th0-2, th0+34)
#define RX 4             // outputs per thread in w (float4 stores)
#define RY 2             // outputs per thread in h
// 256 threads = 16 across (64/4) x 16 down (32/2)

__global__ __launch_bounds__(256, 5) void colwarp_conv_kernel(
    const float* __restrict__ im,
    const float* __restrict__ flat,
    float* __restrict__ out)
{
    const int tilesW = WW / TW;                 // 12
    const int tile   = blockIdx.x;              // 0..287
    const int b      = blockIdx.y;              // 0..31
    const int tw0    = (tile % tilesW) * TW;
    const int th0    = (tile / tilesW) * TH;

    // Mixed (color-warped) channels staged in LDS: 3*36*72*4 = 31104 B -> 5 blocks/CU
    __shared__ float xs[CH][SH][SW];

    const int tid = threadIdx.x;

    // ---- per-sample params (b is block-uniform -> scalar loads / SGPRs) ----
    const float* f = flat + b * 37;
    float Wm[3][3];
#pragma unroll
    for (int d = 0; d < 3; ++d)
#pragma unroll
        for (int c = 0; c < 3; ++c)
            Wm[d][c] = f[d * 3 + c];

    float sh[3];
#pragma unroll
    for (int d = 0; d < 3; ++d) sh[d] = f[9 + d];

    float K[5][5];
#pragma unroll
    for (int i = 0; i < 5; ++i)
#pragma unroll
        for (int j = 0; j < 5; ++j)
            K[i][j] = f[12 + i * 5 + j];

    float bias[3];
#pragma unroll
    for (int c = 0; c < 3; ++c)
        bias[c] = sh[0] * Wm[0][c] + sh[1] * Wm[1][c] + sh[2] * Wm[2][c];

    // ---- stage: float4 loads from all 3 channels, 3x3 mix in registers,
    //      ds_write_b128 of the MIXED channels. Out-of-image -> 0 (padding
    //      applies to the warped image in the reference, so zeros are exact).
    const size_t plane = (size_t)HH * WW;
    const float* im0 = im + (size_t)b * CH * plane;

    for (int u = tid; u < SH * (SW / 4); u += 256) {   // 36*18 = 648 float4 units
        const int r  = u / (SW / 4);
        const int c4 = u - r * (SW / 4);
        const int gh = th0 + r - 2;
        const int gw = tw0 - 4 + c4 * 4;               // 16B aligned; never straddles edge
        float4 m0 = make_float4(0.f, 0.f, 0.f, 0.f);
        float4 m1 = m0, m2 = m0;
        if ((unsigned)gh < (unsigned)HH && (unsigned)gw < (unsigned)WW) {
            const size_t off = (size_t)gh * WW + gw;
            const float4 v0 = *(const float4*)(im0 + off);
            const float4 v1 = *(const float4*)(im0 + plane + off);
            const float4 v2 = *(const float4*)(im0 + 2 * plane + off);
            m0.x = v0.x*Wm[0][0] + v1.x*Wm[1][0] + v2.x*Wm[2][0] + bias[0];
            m0.y = v0.y*Wm[0][0] + v1.y*Wm[1][0] + v2.y*Wm[2][0] + bias[0];
            m0.z = v0.z*Wm[0][0] + v1.z*Wm[1][0] + v2.z*Wm[2][0] + bias[0];
            m0.w = v0.w*Wm[0][0] + v1.w*Wm[1][0] + v2.w*Wm[2][0] + bias[0];
            m1.x = v0.x*Wm[0][1] + v1.x*Wm[1][1] + v2.x*Wm[2][1] + bias[1];
            m1.y = v0.y*Wm[0][1] + v1.y*Wm[1][1] + v2.y*Wm[2][1] + bias[1];
            m1.z = v0.z*Wm[0][1] + v1.z*Wm[1][1] + v2.z*Wm[2][1] + bias[1];
            m1.w = v0.w*Wm[0][1] + v1.w*Wm[1][1] + v2.w*Wm[2][1] + bias[1];
            m2.x = v0.x*Wm[0][2] + v1.x*Wm[1][2] + v2.x*Wm[2][2] + bias[2];
            m2.y = v0.y*Wm[0][2] + v1.y*Wm[1][2] + v2.y*Wm[2][2] + bias[2];
            m2.z = v0.z*Wm[0][2] + v1.z*Wm[1][2] + v2.z*Wm[2][2] + bias[2];
            m2.w = v0.w*Wm[0][2] + v1.w*Wm[1][2] + v2.w*Wm[2][2] + bias[2];
        }
        *(float4*)&xs[0][r][c4 * 4] = m0;
        *(float4*)&xs[1][r][c4 * 4] = m1;
        *(float4*)&xs[2][r][c4 * 4] = m2;
    }
    __syncthreads();

    // ---- conv 5x5 per MIXED channel from LDS, register-blocked RX x RY ----
    const int tx = tid & 15;   // 0..15, 4 output cols each
    const int ty = tid >> 4;   // 0..15, 2 output rows each
    const int r0 = ty * RY;

    float acc[CH][RY][RX];
#pragma unroll
    for (int c = 0; c < CH; ++c)
#pragma unroll
        for (int r = 0; r < RY; ++r)
#pragma unroll
            for (int o = 0; o < RX; ++o)
                acc[c][r][o] = 0.f;

#pragma unroll
    for (int rr = 0; rr < RY + 4; ++rr) {
#pragma unroll
        for (int c = 0; c < CH; ++c) {
            // staged floats [4tx+2 .. 4tx+9] of row r0+rr (8B aligned -> ds_read2_b64)
            const float2* rp = (const float2*)&xs[c][r0 + rr][2 + tx * RX];
            const float2 p0 = rp[0], p1 = rp[1], p2 = rp[2], p3 = rp[3];
            const float w8[8] = {p0.x, p0.y, p1.x, p1.y, p2.x, p2.y, p3.x, p3.y};
#pragma unroll
            for (int i = 0; i < 5; ++i) {
                const int r = rr - i;
                if (r >= 0 && r < RY) {
#pragma unroll
                    for (int j = 0; j < 5; ++j) {
#pragma unroll
                        for (int o = 0; o < RX; ++o)
                            acc[c][r][o] += w8[o + j] * K[i][j];
                    }
                }
            }
        }
    }

    // ---- store: channels already mixed; direct float4 stores ----
#pragma unroll
    for (int c = 0; c < CH; ++c) {
        float* ob = out + ((size_t)b * CH + c) * plane;
#pragma unroll
        for (int r = 0; r < RY; ++r) {
            const float4 v = make_float4(acc[c][r][0], acc[c][r][1],
                                         acc[c][r][2], acc[c][r][3]);
            *(float4*)&ob[(size_t)(th0 + r0 + r) * WW + tw0 + tx * RX] = v;
        }
    }
}

extern "C" void kernel_launch(void* const* d_in, const int* in_sizes, int n_in,
                              void* d_out, int out_size, void* d_ws, size_t ws_size,
                              hipStream_t stream) {
    const float* im   = (const float*)d_in[0];
    const float* flat = (const float*)d_in[1];
    float* out        = (float*)d_out;

    dim3 grid((WW / TW) * (HH / TH), NB);  // (288, 32)
    colwarp_conv_kernel<<<grid, 256, 0, stream>>>(im, flat, out);
}

// Round 5
// 112.709 us; speedup vs baseline: 4.1650x; 1.0050x over previous
//
#include <hip/hip_runtime.h>

// Problem constants (match reference)
#define NB 32
#define CH 3
#define HH 768
#define WW 768

// Tiling
#define TW 64            // output tile width
#define TH 32            // output tile height
#define SW 72            // staged (used) width: [tw0-4, tw0+68)
#define SWP 76           // LDS row stride (pad: 76%32=12 -> ty rows hit distinct banks)
#define SH (TH + 4)      // 36 staged rows: [th0-2, th0+34)
#define RX 4             // outputs per thread in w (float4 stores)
#define RY 2             // outputs per thread in h
// 256 threads = 16 across (64/4) x 16 down (32/2)

__global__ __launch_bounds__(256, 5) void colwarp_conv_kernel(
    const float* __restrict__ im,
    const float* __restrict__ flat,
    float* __restrict__ out)
{
    const int tilesW = WW / TW;                 // 12
    const int tile   = blockIdx.x;              // 0..287
    const int b      = blockIdx.y;              // 0..31
    const int tw0    = (tile % tilesW) * TW;
    const int th0    = (tile / tilesW) * TH;

    // Mixed (color-warped) channels staged in LDS: 3*36*76*4 = 32832 B -> 4 blocks/CU
    __shared__ float xs[CH][SH][SWP];

    const int tid = threadIdx.x;

    // ---- per-sample params (b is block-uniform -> scalar loads / SGPRs) ----
    const float* f = flat + b * 37;
    float Wm[3][3];
#pragma unroll
    for (int d = 0; d < 3; ++d)
#pragma unroll
        for (int c = 0; c < 3; ++c)
            Wm[d][c] = f[d * 3 + c];

    float sh[3];
#pragma unroll
    for (int d = 0; d < 3; ++d) sh[d] = f[9 + d];

    float K[5][5];
#pragma unroll
    for (int i = 0; i < 5; ++i)
#pragma unroll
        for (int j = 0; j < 5; ++j)
            K[i][j] = f[12 + i * 5 + j];

    float bias[3];
#pragma unroll
    for (int c = 0; c < 3; ++c)
        bias[c] = sh[0] * Wm[0][c] + sh[1] * Wm[1][c] + sh[2] * Wm[2][c];

    // ---- stage: float4 loads from all 3 channels, 3x3 mix in registers,
    //      ds_write_b128 of the MIXED channels. Out-of-image -> 0 (padding
    //      applies to the warped image in the reference, so zeros are exact).
    const size_t plane = (size_t)HH * WW;
    const float* im0 = im + (size_t)b * CH * plane;

    for (int u = tid; u < SH * (SW / 4); u += 256) {   // 36*18 = 648 float4 units
        const int r  = u / (SW / 4);
        const int c4 = u - r * (SW / 4);
        const int gh = th0 + r - 2;
        const int gw = tw0 - 4 + c4 * 4;               // 16B aligned; never straddles edge
        float4 m0 = make_float4(0.f, 0.f, 0.f, 0.f);
        float4 m1 = m0, m2 = m0;
        if ((unsigned)gh < (unsigned)HH && (unsigned)gw < (unsigned)WW) {
            const size_t off = (size_t)gh * WW + gw;
            const float4 v0 = *(const float4*)(im0 + off);
            const float4 v1 = *(const float4*)(im0 + plane + off);
            const float4 v2 = *(const float4*)(im0 + 2 * plane + off);
            m0.x = v0.x*Wm[0][0] + v1.x*Wm[1][0] + v2.x*Wm[2][0] + bias[0];
            m0.y = v0.y*Wm[0][0] + v1.y*Wm[1][0] + v2.y*Wm[2][0] + bias[0];
            m0.z = v0.z*Wm[0][0] + v1.z*Wm[1][0] + v2.z*Wm[2][0] + bias[0];
            m0.w = v0.w*Wm[0][0] + v1.w*Wm[1][0] + v2.w*Wm[2][0] + bias[0];
            m1.x = v0.x*Wm[0][1] + v1.x*Wm[1][1] + v2.x*Wm[2][1] + bias[1];
            m1.y = v0.y*Wm[0][1] + v1.y*Wm[1][1] + v2.y*Wm[2][1] + bias[1];
            m1.z = v0.z*Wm[0][1] + v1.z*Wm[1][1] + v2.z*Wm[2][1] + bias[1];
            m1.w = v0.w*Wm[0][1] + v1.w*Wm[1][1] + v2.w*Wm[2][1] + bias[1];
            m2.x = v0.x*Wm[0][2] + v1.x*Wm[1][2] + v2.x*Wm[2][2] + bias[2];
            m2.y = v0.y*Wm[0][2] + v1.y*Wm[1][2] + v2.y*Wm[2][2] + bias[2];
            m2.z = v0.z*Wm[0][2] + v1.z*Wm[1][2] + v2.z*Wm[2][2] + bias[2];
            m2.w = v0.w*Wm[0][2] + v1.w*Wm[1][2] + v2.w*Wm[2][2] + bias[2];
        }
        *(float4*)&xs[0][r][c4 * 4] = m0;
        *(float4*)&xs[1][r][c4 * 4] = m1;
        *(float4*)&xs[2][r][c4 * 4] = m2;
    }
    __syncthreads();

    // ---- conv 5x5 per MIXED channel from LDS, register-blocked RX x RY ----
    const int tx = tid & 15;   // 0..15, 4 output cols each
    const int ty = tid >> 4;   // 0..15, 2 output rows each
    const int r0 = ty * RY;

    float acc[CH][RY][RX];
#pragma unroll
    for (int c = 0; c < CH; ++c)
#pragma unroll
        for (int r = 0; r < RY; ++r)
#pragma unroll
            for (int o = 0; o < RX; ++o)
                acc[c][r][o] = 0.f;

#pragma unroll
    for (int rr = 0; rr < RY + 4; ++rr) {
#pragma unroll
        for (int c = 0; c < CH; ++c) {
            // staged floats [4tx+2 .. 4tx+9] of row r0+rr (8B aligned -> ds_read2_b64)
            const float2* rp = (const float2*)&xs[c][r0 + rr][2 + tx * RX];
            const float2 p0 = rp[0], p1 = rp[1], p2 = rp[2], p3 = rp[3];
            const float w8[8] = {p0.x, p0.y, p1.x, p1.y, p2.x, p2.y, p3.x, p3.y};
#pragma unroll
            for (int i = 0; i < 5; ++i) {
                const int r = rr - i;
                if (r >= 0 && r < RY) {
#pragma unroll
                    for (int j = 0; j < 5; ++j) {
#pragma unroll
                        for (int o = 0; o < RX; ++o)
                            acc[c][r][o] += w8[o + j] * K[i][j];
                    }
                }
            }
        }
    }

    // ---- store: channels already mixed; direct float4 stores ----
#pragma unroll
    for (int c = 0; c < CH; ++c) {
        float* ob = out + ((size_t)b * CH + c) * plane;
#pragma unroll
        for (int r = 0; r < RY; ++r) {
            const float4 v = make_float4(acc[c][r][0], acc[c][r][1],
                                         acc[c][r][2], acc[c][r][3]);
            *(float4*)&ob[(size_t)(th0 + r0 + r) * WW + tw0 + tx * RX] = v;
        }
    }
}

extern "C" void kernel_launch(void* const* d_in, const int* in_sizes, int n_in,
                              void* d_out, int out_size, void* d_ws, size_t ws_size,
                              hipStream_t stream) {
    const float* im   = (const float*)d_in[0];
    const float* flat = (const float*)d_in[1];
    float* out        = (float*)d_out;

    dim3 grid((WW / TW) * (HH / TH), NB);  // (288, 32)
    colwarp_conv_kernel<<<grid, 256, 0, stream>>>(im, flat, out);
}